// Round 1
// baseline (169.133 us; speedup 1.0000x reference)
//
#include <hip/hip_runtime.h>
#include <hip/hip_bf16.h>

// LocallyConnected1d: x (64,64,1024) f32, weights (1024,64,64,9) f32, bias (64,1024) f32
// out[b*65536 + w*64 + o] = sum_{c,k} x[b,c,w+k-4] * weights[w,o,c,k] + bias_flat[w*64+o]
// Per-w GEMM: M=64 (batch), N=64 (o), K=576 (c*9+k). bf16 MFMA, fp32 accumulate.

typedef __bf16 bf16x8 __attribute__((ext_vector_type(8)));
typedef float  f32x4  __attribute__((ext_vector_type(4)));

#define NK     576   // C_in * 9
#define PHK    288   // K per phase (c in blocks of 32)
#define LDAP   296   // 288 + 8 pad: row stride 592B -> 2-way bank access on ds_read_b128
#define NITER  9     // 288 / 32

__global__ __launch_bounds__(256, 4)
void lc1d_mfma_kernel(const float* __restrict__ x,
                      const float* __restrict__ wts,
                      const float* __restrict__ bias,
                      float* __restrict__ out) {
    __shared__ __bf16 Alds[64][LDAP];

    const int w     = blockIdx.x;
    const int tid   = threadIdx.x;
    const int lane  = tid & 63;
    const int wv    = tid >> 6;          // wave 0..3 -> o strip
    const int row16 = lane & 15;
    const int ko    = (lane >> 4) * 8;   // k sub-offset within 32-chunk
    const int o     = wv * 16 + row16;

    // weights row for this lane's output column o: weights[w][o][.] is 576 contiguous f32
    const float* wbase = wts + (size_t)w * (64 * NK) + (size_t)o * NK + ko;

    f32x4 acc[4];
    #pragma unroll
    for (int i = 0; i < 4; ++i) { acc[i][0]=0.f; acc[i][1]=0.f; acc[i][2]=0.f; acc[i][3]=0.f; }

    const int xbase = w - 4;

    for (int ph = 0; ph < 2; ++ph) {
        if (ph) __syncthreads();   // WAR: all waves done reading phase-0 LDS

        // Stage x window -> LDS bf16. 64 b x 32 c = 2048 rows of 9 taps; 8 per thread.
        #pragma unroll
        for (int i = 0; i < 8; ++i) {
            int pair = i * 256 + tid;
            int b  = pair >> 5;
            int cl = pair & 31;
            int c  = ph * 32 + cl;
            const float* xrow = x + ((size_t)(b * 64 + c) << 10);
            __bf16* dst = &Alds[b][cl * 9];
            #pragma unroll
            for (int t = 0; t < 9; ++t) {
                int pos = xbase + t;
                float v = (pos >= 0 && pos < 1024) ? xrow[pos] : 0.0f;
                dst[t] = (__bf16)v;
            }
        }
        __syncthreads();

        const float* wp = wbase + ph * PHK;
        #pragma unroll
        for (int it = 0; it < NITER; ++it) {
            const int kk0 = it * 32;
            // B fragment: 8 consecutive f32 weights -> bf16 (aligned 16B)
            f32x4 w0 = *reinterpret_cast<const f32x4*>(wp + kk0);
            f32x4 w1 = *reinterpret_cast<const f32x4*>(wp + kk0 + 4);
            bf16x8 bf;
            #pragma unroll
            for (int j = 0; j < 4; ++j) { bf[j] = (__bf16)w0[j]; bf[j + 4] = (__bf16)w1[j]; }
            // A fragments: 4 b-tiles of 16 rows
            #pragma unroll
            for (int bt = 0; bt < 4; ++bt) {
                bf16x8 af = *reinterpret_cast<const bf16x8*>(&Alds[bt * 16 + row16][kk0 + ko]);
                acc[bt] = __builtin_amdgcn_mfma_f32_16x16x32_bf16(af, bf, acc[bt], 0, 0, 0);
            }
        }
    }

    // Epilogue: out[b*65536 + w*64 + o] = acc + bias_flat[w*64+o]
    const float bv = bias[w * 64 + o];
    const int r0 = (lane >> 4) * 4;
    float* outp = out + (size_t)w * 64 + o;
    #pragma unroll
    for (int bt = 0; bt < 4; ++bt) {
        #pragma unroll
        for (int r = 0; r < 4; ++r) {
            int b = bt * 16 + r0 + r;
            outp[(size_t)b * 65536] = acc[bt][r] + bv;
        }
    }
}

extern "C" void kernel_launch(void* const* d_in, const int* in_sizes, int n_in,
                              void* d_out, int out_size, void* d_ws, size_t ws_size,
                              hipStream_t stream) {
    const float* x    = (const float*)d_in[0];
    const float* wts  = (const float*)d_in[1];
    const float* bias = (const float*)d_in[2];
    float* out = (float*)d_out;
    lc1d_mfma_kernel<<<dim3(1024), dim3(256), 0, stream>>>(x, wts, bias, out);
}

// Round 2
// 72.809 us; speedup vs baseline: 2.3230x; 2.3230x over previous
//
#include <hip/hip_runtime.h>
#include <hip/hip_bf16.h>

// LocallyConnected1d: x (64,64,1024) f32, weights (1024,64,64,9) f32, bias (64,1024) f32
// out[b*65536 + w*64 + o] = sum_{c,k} x[b,c,w+k-4] * weights[w,o,c,k] + bias_flat[w*64+o]
// Per-w GEMM: M=64 (batch), N=64 (o), K=576 (c*9+k). bf16 MFMA, fp32 accumulate.

typedef __bf16 bf16x8 __attribute__((ext_vector_type(8)));
typedef float  f32x4  __attribute__((ext_vector_type(4)));

#define NK     576   // C_in * 9
#define PHK    288   // K per phase (c in blocks of 32)
#define LDAP   296   // 288 + 8 pad
#define NITER  9     // 288 / 32

__global__ __launch_bounds__(256, 4)
void lc1d_mfma_kernel(const float* __restrict__ x,
                      const float* __restrict__ wts,
                      const float* __restrict__ bias,
                      float* __restrict__ out) {
    __shared__ __bf16 Alds[64][LDAP];

    const int w     = blockIdx.x;
    const int tid   = threadIdx.x;
    const int lane  = tid & 63;
    const int wv    = tid >> 6;          // wave 0..3 -> o strip
    const int row16 = lane & 15;
    const int ko    = (lane >> 4) * 8;   // k sub-offset within 32-chunk
    const int o     = wv * 16 + row16;

    const float* wbase = wts + (size_t)w * (64 * NK) + (size_t)o * NK + ko;

    // staging geometry: 4 lanes per (b,c) row, each loads one aligned f32x4
    const int xbase  = w - 4;
    const int a0     = xbase & ~3;       // aligned window start (may be -4)
    const int d      = xbase - a0;       // 0..3 shift
    const int rowsel = tid >> 2;         // 0..63: which row this 4-lane group handles
    const int sl     = tid & 3;          // sub-lane: which f32x4 of the window
    const int p0     = a0 + sl * 4;      // this lane's 4 positions p0..p0+3 (4-aligned)
    const bool inb   = (p0 >= 0) && (p0 < 1024);   // all-in or all-out (bounds are x4)

    f32x4 acc[4];
    #pragma unroll
    for (int i = 0; i < 4; ++i) acc[i] = (f32x4){0.f, 0.f, 0.f, 0.f};

    #pragma unroll
    for (int ph = 0; ph < 2; ++ph) {
        // ---- prefetch this phase's weights into registers (overlaps staging) ----
        f32x4 wr[2 * NITER];
        const float* wp = wbase + ph * PHK;
        #pragma unroll
        for (int it = 0; it < NITER; ++it) {
            wr[2 * it]     = *reinterpret_cast<const f32x4*>(wp + it * 32);
            wr[2 * it + 1] = *reinterpret_cast<const f32x4*>(wp + it * 32 + 4);
        }

        if (ph) __syncthreads();   // WAR: waves done reading previous phase's LDS

        // ---- stage x window -> dense bf16 LDS ----
        // 2048 rows (64 b x 32 c) per phase; 64 rows per iteration (16 rows/wave-instr)
        #pragma unroll 4
        for (int i = 0; i < 32; ++i) {
            int R  = i * 64 + rowsel;
            int b  = R >> 5;
            int cl = R & 31;
            int c  = ph * 32 + cl;
            f32x4 v = (f32x4){0.f, 0.f, 0.f, 0.f};
            if (inb) v = *reinterpret_cast<const f32x4*>(x + (((size_t)(b * 64 + c)) << 10) + p0);
            __bf16* dst = &Alds[b][cl * 9];
            #pragma unroll
            for (int j = 0; j < 4; ++j) {
                int t = sl * 4 + j - d;          // window tap index
                if (t >= 0 && t <= 8) dst[t] = (__bf16)v[j];
            }
        }
        __syncthreads();

        // ---- MFMA over this phase's K ----
        #pragma unroll
        for (int it = 0; it < NITER; ++it) {
            bf16x8 bf;
            #pragma unroll
            for (int j = 0; j < 4; ++j) {
                bf[j]     = (__bf16)wr[2 * it][j];
                bf[j + 4] = (__bf16)wr[2 * it + 1][j];
            }
            const int kk0 = it * 32;
            #pragma unroll
            for (int bt = 0; bt < 4; ++bt) {
                bf16x8 af = *reinterpret_cast<const bf16x8*>(&Alds[bt * 16 + row16][kk0 + ko]);
                acc[bt] = __builtin_amdgcn_mfma_f32_16x16x32_bf16(af, bf, acc[bt], 0, 0, 0);
            }
        }
    }

    // ---- epilogue ----
    const float bv = bias[w * 64 + o];
    const int r0 = (lane >> 4) * 4;
    float* outp = out + (size_t)w * 64 + o;
    #pragma unroll
    for (int bt = 0; bt < 4; ++bt) {
        #pragma unroll
        for (int r = 0; r < 4; ++r) {
            int b = bt * 16 + r0 + r;
            outp[(size_t)b * 65536] = acc[bt][r] + bv;
        }
    }
}

extern "C" void kernel_launch(void* const* d_in, const int* in_sizes, int n_in,
                              void* d_out, int out_size, void* d_ws, size_t ws_size,
                              hipStream_t stream) {
    const float* x    = (const float*)d_in[0];
    const float* wts  = (const float*)d_in[1];
    const float* bias = (const float*)d_in[2];
    float* out = (float*)d_out;
    lc1d_mfma_kernel<<<dim3(1024), dim3(256), 0, stream>>>(x, wts, bias, out);
}